// Round 1
// baseline (3870.425 us; speedup 1.0000x reference)
//
#include <hip/hip_runtime.h>
#include <cstdint>

#define NN 8192
#define TT 64
#define EE 262144

typedef __attribute__((ext_vector_type(8))) short short8;
typedef __attribute__((ext_vector_type(4))) float f32x4;

__device__ __forceinline__ f32x4 mfma16(short8 a, short8 b, f32x4 c) {
    return __builtin_amdgcn_mfma_f32_16x16x32_bf16(a, b, c, 0, 0, 0);
}
__device__ __forceinline__ unsigned short f2bf(float f) {
    uint32_t u = __float_as_uint(f);
    u += 0x7fff + ((u >> 16) & 1);
    return (unsigned short)(u >> 16);
}
__device__ __forceinline__ float bf2f(unsigned short s) {
    return __uint_as_float(((uint32_t)s) << 16);
}
__device__ __forceinline__ float sigm(float x) { return 1.0f / (1.0f + __expf(-x)); }
__device__ __forceinline__ float tanh_(float x) { float e = __expf(2.0f * x); return 1.0f - 2.0f / (e + 1.0f); }

// ---------- prep ----------
__global__ void k_prep_whh(const float* __restrict__ w, unsigned short* __restrict__ o) {
    int i = (blockIdx.x * 256 + threadIdx.x) * 4;  // 256 blocks -> 262144
    float4 v = *(const float4*)(w + i);
    uint32_t p0 = (uint32_t)f2bf(v.x) | ((uint32_t)f2bf(v.y) << 16);
    uint32_t p1 = (uint32_t)f2bf(v.z) | ((uint32_t)f2bf(v.w) << 16);
    *(uint2*)(o + i) = make_uint2(p0, p1);
}

__global__ void k_prep_misc(const float* __restrict__ x, float* __restrict__ xc, int* __restrict__ deg) {
    int i = blockIdx.x * 256 + threadIdx.x;
    if (i < NN) { xc[i] = x[i * TT + (TT - 1)]; deg[i] = 0; }
}

__global__ void k_hist(const int* __restrict__ ei, int* __restrict__ deg) {
    int e = blockIdx.x * 256 + threadIdx.x;
    if (e < EE) atomicAdd(&deg[ei[EE + e]], 1);
}

__global__ __launch_bounds__(1024) void k_scan(const int* __restrict__ deg, int* __restrict__ row_start,
                                               int* __restrict__ cursor, float* __restrict__ dinv) {
    __shared__ int sc[1024];
    int tid = threadIdx.x;
    int base[8]; int s = 0;
#pragma unroll
    for (int i = 0; i < 8; ++i) { base[i] = s; s += deg[tid * 8 + i]; }
    sc[tid] = s; __syncthreads();
    for (int off = 1; off < 1024; off <<= 1) {
        int v = (tid >= off) ? sc[tid - off] : 0;
        __syncthreads();
        sc[tid] += v;
        __syncthreads();
    }
    int excl = (tid > 0) ? sc[tid - 1] : 0;
#pragma unroll
    for (int i = 0; i < 8; ++i) {
        int rsv = excl + base[i];
        row_start[tid * 8 + i] = rsv;
        cursor[tid * 8 + i] = rsv;
        dinv[tid * 8 + i] = rsqrtf((float)(deg[tid * 8 + i] + 1));
    }
    if (tid == 0) row_start[NN] = sc[1023];
}

__global__ void k_fill(const int* __restrict__ ei, int* __restrict__ cursor, int* __restrict__ csr_src) {
    int e = blockIdx.x * 256 + threadIdx.x;
    if (e < EE) {
        int d = ei[EE + e];
        int pos = atomicAdd(&cursor[d], 1);
        csr_src[pos] = ei[e];
    }
}

// ---------- LSTM: 128 blocks x 64 rows, persistent over 64 steps ----------
// wave w owns units {u*64 + w*16 + cc} per chunk u; all 64 rows; acc 16 tiles.
__global__ __launch_bounds__(256, 1) void k_lstm(
    const float* __restrict__ x, const unsigned short* __restrict__ whh,
    const float* __restrict__ wih, const float* __restrict__ bih,
    const float* __restrict__ bhh, float* __restrict__ hout) {
    __shared__ unsigned short hl[64][264];
    __shared__ float wihl[1024];
    __shared__ float biasl[1024];
    const int tid = threadIdx.x;
    const int m0 = blockIdx.x * 64;
    for (int i = tid; i < 1024; i += 256) { wihl[i] = wih[i]; biasl[i] = bih[i] + bhh[i]; }
    for (int i = tid; i < 64 * 264; i += 256) ((unsigned short*)hl)[i] = 0;
    __syncthreads();
    const int lane = tid & 63, wave = tid >> 6;
    const int q = lane >> 4, cc = lane & 15;
    float c_reg[64];
#pragma unroll
    for (int i = 0; i < 64; ++i) c_reg[i] = 0.f;

    for (int t = 0; t < TT; ++t) {
        float xr[16];
#pragma unroll
        for (int rt = 0; rt < 4; ++rt)
#pragma unroll
            for (int r = 0; r < 4; ++r)
                xr[rt * 4 + r] = x[(m0 + rt * 16 + q * 4 + r) * TT + t];

        uint32_t hnew[32];
#pragma unroll
        for (int u = 0; u < 4; ++u) {
            f32x4 acc[16];
#pragma unroll
            for (int i = 0; i < 16; ++i) acc[i] = (f32x4)(0.0f);
#pragma unroll
            for (int ks = 0; ks < 8; ++ks) {
                short8 af[4];
#pragma unroll
                for (int rt = 0; rt < 4; ++rt)
                    af[rt] = *(const short8*)&hl[rt * 16 + cc][ks * 32 + q * 8];
#pragma unroll
                for (int g = 0; g < 4; ++g) {
                    const int wrow = g * 256 + u * 64 + wave * 16 + cc;
                    const short8 bfr = *(const short8*)(whh + wrow * 256 + ks * 32 + q * 8);
#pragma unroll
                    for (int rt = 0; rt < 4; ++rt)
                        acc[rt * 4 + g] = mfma16(af[rt], bfr, acc[rt * 4 + g]);
                }
            }
            const int unit = u * 64 + wave * 16 + cc;
            const float wi_ = wihl[unit], wf_ = wihl[256 + unit], wg_ = wihl[512 + unit], wo_ = wihl[768 + unit];
            const float bi_ = biasl[unit], bf_ = biasl[256 + unit], bg_ = biasl[512 + unit], bo_ = biasl[768 + unit];
#pragma unroll
            for (int rt = 0; rt < 4; ++rt) {
#pragma unroll
                for (int r = 0; r < 4; ++r) {
                    const float xv = xr[rt * 4 + r];
                    float vi = acc[rt * 4 + 0][r] + xv * wi_ + bi_;
                    float vf = acc[rt * 4 + 1][r] + xv * wf_ + bf_;
                    float vg = acc[rt * 4 + 2][r] + xv * wg_ + bg_;
                    float vo = acc[rt * 4 + 3][r] + xv * wo_ + bo_;
                    const int ci = u * 16 + rt * 4 + r;
                    float cv = sigm(vf) * c_reg[ci] + sigm(vi) * tanh_(vg);
                    c_reg[ci] = cv;
                    unsigned short h16 = f2bf(sigm(vo) * tanh_(cv));
                    const int hi = u * 8 + rt * 2 + (r >> 1);
                    if ((r & 1) == 0) hnew[hi] = (uint32_t)h16;
                    else hnew[hi] |= ((uint32_t)h16) << 16;
                }
            }
        }
        __syncthreads();  // all MFMA reads of h done
#pragma unroll
        for (int u = 0; u < 4; ++u) {
            const int unit = u * 64 + wave * 16 + cc;
#pragma unroll
            for (int rt = 0; rt < 4; ++rt)
#pragma unroll
                for (int r = 0; r < 4; ++r) {
                    const int row = rt * 16 + q * 4 + r;
                    uint32_t pv = hnew[u * 8 + rt * 2 + (r >> 1)];
                    unsigned short h16 = (r & 1) ? (unsigned short)(pv >> 16) : (unsigned short)(pv & 0xffff);
                    hl[row][unit] = h16;
                }
        }
        __syncthreads();  // writes visible before next step's reads
    }
    for (int i = tid; i < 64 * 256; i += 256) {
        int r = i >> 8, k = i & 255;
        hout[(size_t)(m0 + r) * 256 + k] = bf2f(hl[r][k]);
    }
}

// ---------- s1 = sadj@xc, f1 = fadj@xc ----------
__global__ __launch_bounds__(256) void k_matvec(const float* __restrict__ sadj, const float* __restrict__ fadj,
                                                const float* __restrict__ xc, float* __restrict__ s1,
                                                float* __restrict__ f1) {
    const float* A = blockIdx.y ? fadj : sadj;
    float* out = blockIdx.y ? f1 : s1;
    const int row = blockIdx.x, tid = threadIdx.x;
    const float4* a4 = (const float4*)(A + (size_t)row * NN);
    const float4* x4 = (const float4*)xc;
    float acc = 0.f;
#pragma unroll
    for (int c = 0; c < 8; ++c) {
        float4 a = a4[c * 256 + tid];
        float4 v = x4[c * 256 + tid];
        acc += a.x * v.x + a.y * v.y + a.z * v.z + a.w * v.w;
    }
#pragma unroll
    for (int o = 32; o; o >>= 1) acc += __shfl_xor(acc, o);
    __shared__ float red[4];
    if ((tid & 63) == 0) red[tid >> 6] = acc;
    __syncthreads();
    if (tid == 0) out[row] = red[0] + red[1] + red[2] + red[3];
}

// ---------- BsT[j][n] = (relu(s1[n]*W1 + b1) @ W2)[n][j] in bf16, transposed ----------
__global__ __launch_bounds__(256) void k_buildB(
    const float* __restrict__ s1, const float* __restrict__ f1,
    const float* __restrict__ sg1W, const float* __restrict__ sg1b, const float* __restrict__ sg2W,
    const float* __restrict__ dg1W, const float* __restrict__ dg1b, const float* __restrict__ dg2W,
    unsigned short* __restrict__ BsT, unsigned short* __restrict__ BdT) {
    const int mat = blockIdx.y;
    const float* sv = mat ? f1 : s1;
    const float* W1 = mat ? dg1W : sg1W;
    const float* b1 = mat ? dg1b : sg1b;
    const float* W2 = mat ? dg2W : sg2W;
    unsigned short* BT = mat ? BdT : BsT;
    const int n0 = blockIdx.x * 8;
    const int tid = threadIdx.x;
    __shared__ float h[8][256];
    __shared__ float sl[8];
    if (tid < 8) sl[tid] = sv[n0 + tid];
    __syncthreads();
    {
        float w1 = W1[tid], bb = b1[tid];
#pragma unroll
        for (int g = 0; g < 8; ++g) h[g][tid] = fmaxf(sl[g] * w1 + bb, 0.f);
    }
    __syncthreads();
    float acc[8];
#pragma unroll
    for (int g = 0; g < 8; ++g) acc[g] = 0.f;
    for (int kb = 0; kb < 64; ++kb) {
        float4 h4[8];
#pragma unroll
        for (int g = 0; g < 8; ++g) h4[g] = *(const float4*)&h[g][kb * 4];
#pragma unroll
        for (int dk = 0; dk < 4; ++dk) {
            float w = W2[(kb * 4 + dk) * 256 + tid];
#pragma unroll
            for (int g = 0; g < 8; ++g) acc[g] += ((const float*)&h4[g])[dk] * w;
        }
    }
    uint32_t p[4];
#pragma unroll
    for (int i = 0; i < 4; ++i)
        p[i] = (uint32_t)f2bf(acc[2 * i]) | ((uint32_t)f2bf(acc[2 * i + 1]) << 16);
    uint4 pv = make_uint4(p[0], p[1], p[2], p[3]);
    *(uint4*)(BT + (size_t)tid * NN + n0) = pv;
}

// ---------- gs = sadj @ Bs + b2 (fp32 A converted to bf16 on the fly) ----------
__global__ __launch_bounds__(256, 1) void k_adjgemm(
    const float* __restrict__ sadj, const float* __restrict__ fadj,
    const unsigned short* __restrict__ BsT, const unsigned short* __restrict__ BdT,
    const float* __restrict__ sb2, const float* __restrict__ db2,
    float* __restrict__ gs, float* __restrict__ gd) {
    const int bx = blockIdx.x;
    const int mat = bx >> 7, strip = bx & 127;
    const float* A = mat ? fadj : sadj;
    const unsigned short* BT = mat ? BdT : BsT;
    const float* bias = mat ? db2 : sb2;
    float* C = mat ? gd : gs;
    __shared__ unsigned short Al[2][64][40];
    __shared__ unsigned short Bl[2][256][40];
    const int tid = threadIdx.x;
    const int lane = tid & 63, wave = tid >> 6;
    const int q = lane >> 4, cc = lane & 15;

    f32x4 acc[16];
#pragma unroll
    for (int i = 0; i < 16; ++i) acc[i] = (f32x4)(0.0f);

    float4 apf[2]; uint4 bpf[4];
#pragma unroll
    for (int c = 0; c < 2; ++c) {
        int id = c * 256 + tid; int r = id >> 3, kc = id & 7;
        apf[c] = *(const float4*)(A + (size_t)(strip * 64 + r) * NN + kc * 4);
    }
#pragma unroll
    for (int i = 0; i < 4; ++i) {
        int id = i * 256 + tid; int col = id >> 2, j = id & 3;
        bpf[i] = *(const uint4*)(BT + (size_t)col * NN + j * 8);
    }
    int buf = 0;
#pragma unroll
    for (int c = 0; c < 2; ++c) {
        int id = c * 256 + tid; int r = id >> 3, kc = id & 7;
        uint32_t p0 = (uint32_t)f2bf(apf[c].x) | ((uint32_t)f2bf(apf[c].y) << 16);
        uint32_t p1 = (uint32_t)f2bf(apf[c].z) | ((uint32_t)f2bf(apf[c].w) << 16);
        *(uint2*)&Al[0][r][kc * 4] = make_uint2(p0, p1);
    }
#pragma unroll
    for (int i = 0; i < 4; ++i) {
        int id = i * 256 + tid; int col = id >> 2, j = id & 3;
        *(uint4*)&Bl[0][col][j * 8] = bpf[i];
    }
    __syncthreads();

    for (int kb = 0; kb < 256; ++kb) {
        const int k1 = (kb + 1) * 32;
        if (kb < 255) {
#pragma unroll
            for (int c = 0; c < 2; ++c) {
                int id = c * 256 + tid; int r = id >> 3, kc = id & 7;
                apf[c] = *(const float4*)(A + (size_t)(strip * 64 + r) * NN + k1 + kc * 4);
            }
#pragma unroll
            for (int i = 0; i < 4; ++i) {
                int id = i * 256 + tid; int col = id >> 2, j = id & 3;
                bpf[i] = *(const uint4*)(BT + (size_t)col * NN + k1 + j * 8);
            }
        }
        short8 af[4], bfm[4];
#pragma unroll
        for (int rt = 0; rt < 4; ++rt) af[rt] = *(const short8*)&Al[buf][rt * 16 + cc][q * 8];
#pragma unroll
        for (int ct = 0; ct < 4; ++ct) bfm[ct] = *(const short8*)&Bl[buf][wave * 64 + ct * 16 + cc][q * 8];
#pragma unroll
        for (int rt = 0; rt < 4; ++rt)
#pragma unroll
            for (int ct = 0; ct < 4; ++ct)
                acc[rt * 4 + ct] = mfma16(af[rt], bfm[ct], acc[rt * 4 + ct]);
        if (kb < 255) {
#pragma unroll
            for (int c = 0; c < 2; ++c) {
                int id = c * 256 + tid; int r = id >> 3, kc = id & 7;
                uint32_t p0 = (uint32_t)f2bf(apf[c].x) | ((uint32_t)f2bf(apf[c].y) << 16);
                uint32_t p1 = (uint32_t)f2bf(apf[c].z) | ((uint32_t)f2bf(apf[c].w) << 16);
                *(uint2*)&Al[buf ^ 1][r][kc * 4] = make_uint2(p0, p1);
            }
#pragma unroll
            for (int i = 0; i < 4; ++i) {
                int id = i * 256 + tid; int col = id >> 2, j = id & 3;
                *(uint4*)&Bl[buf ^ 1][col][j * 8] = bpf[i];
            }
            __syncthreads();
            buf ^= 1;
        }
    }
#pragma unroll
    for (int rt = 0; rt < 4; ++rt)
#pragma unroll
        for (int ct = 0; ct < 4; ++ct) {
            const int gcol = wave * 64 + ct * 16 + cc;
            const float bb = bias[gcol];
#pragma unroll
            for (int r = 0; r < 4; ++r) {
                const int grow = strip * 64 + rt * 16 + q * 4 + r;
                C[(size_t)grow * 256 + gcol] = acc[rt * 4 + ct][r] + bb;
            }
        }
}

// ---------- attention + gate + fuse (wave per node) ----------
__global__ __launch_bounds__(256) void k_fuse(
    const float* __restrict__ gs, const float* __restrict__ gd, const float* __restrict__ hlstm,
    const float* __restrict__ attW1, const float* __restrict__ attb1, const float* __restrict__ attW2,
    const float* __restrict__ gateW, const float* __restrict__ gateb, float* __restrict__ fused) {
    const int tid = threadIdx.x, lane = tid & 63, wave = tid >> 6;
    const int n = blockIdx.x * 4 + wave;
    float4 vs = *(const float4*)(gs + (size_t)n * 256 + lane * 4);
    float4 vd = *(const float4*)(gd + (size_t)n * 256 + lane * 4);
    float vsa[4] = {vs.x, vs.y, vs.z, vs.w};
    float vda[4] = {vd.x, vd.y, vd.z, vd.w};
    float vca[4];
#pragma unroll
    for (int i = 0; i < 4; ++i) vca[i] = 0.5f * (vsa[i] + vda[i]);
    float y[3][16];
#pragma unroll
    for (int v = 0; v < 3; ++v)
#pragma unroll
        for (int hh = 0; hh < 16; ++hh) y[v][hh] = 0.f;
#pragma unroll
    for (int t = 0; t < 4; ++t) {
        const int k = lane * 4 + t;
#pragma unroll
        for (int hb = 0; hb < 4; ++hb) {
            float4 w = *(const float4*)(attW1 + k * 16 + hb * 4);
            float wa[4] = {w.x, w.y, w.z, w.w};
#pragma unroll
            for (int j = 0; j < 4; ++j) {
                y[0][hb * 4 + j] += vsa[t] * wa[j];
                y[1][hb * 4 + j] += vda[t] * wa[j];
                y[2][hb * 4 + j] += vca[t] * wa[j];
            }
        }
    }
#pragma unroll
    for (int v = 0; v < 3; ++v)
#pragma unroll
        for (int hh = 0; hh < 16; ++hh) {
            float a = y[v][hh];
#pragma unroll
            for (int o = 32; o; o >>= 1) a += __shfl_xor(a, o);
            y[v][hh] = a;
        }
    float wv[3];
#pragma unroll
    for (int v = 0; v < 3; ++v) {
        float s = 0.f;
#pragma unroll
        for (int hh = 0; hh < 16; ++hh) s += tanh_(y[v][hh] + attb1[hh]) * attW2[hh];
        wv[v] = s;
    }
    float mx = fmaxf(wv[0], fmaxf(wv[1], wv[2]));
    float e0 = __expf(wv[0] - mx), e1 = __expf(wv[1] - mx), e2 = __expf(wv[2] - mx);
    float inv = 1.f / (e0 + e1 + e2);
    float b0 = e0 * inv, b1v = e1 * inv, b2 = e2 * inv;
    float gf[4];
#pragma unroll
    for (int i = 0; i < 4; ++i) gf[i] = b0 * vsa[i] + b1v * vda[i] + b2 * vca[i];
    float4 hv4 = *(const float4*)(hlstm + (size_t)n * 256 + lane * 4);
    float hva[4] = {hv4.x, hv4.y, hv4.z, hv4.w};
    float4 w0 = *(const float4*)(gateW + lane * 4);
    float4 w1 = *(const float4*)(gateW + 256 + lane * 4);
    float part = gf[0] * w0.x + gf[1] * w0.y + gf[2] * w0.z + gf[3] * w0.w +
                 hva[0] * w1.x + hva[1] * w1.y + hva[2] * w1.z + hva[3] * w1.w;
#pragma unroll
    for (int o = 32; o; o >>= 1) part += __shfl_xor(part, o);
    float z = sigm(part + gateb[0]);
    float4 fo;
    fo.x = z * gf[0] + (1.f - z) * hva[0];
    fo.y = z * gf[1] + (1.f - z) * hva[1];
    fo.z = z * gf[2] + (1.f - z) * hva[2];
    fo.w = z * gf[3] + (1.f - z) * hva[3];
    *(float4*)(fused + (size_t)n * 256 + lane * 4) = fo;
}

// ---------- small GEMM xw = A(8192xK=256) @ W(256xP) ----------
template <int P>
__global__ __launch_bounds__(256) void k_xw(const float* __restrict__ A, const float* __restrict__ W,
                                            float* __restrict__ out) {
    constexpr int CPT = 256 / P;
    constexpr int RT = 32 / CPT;
    __shared__ float Al[32][256];
    const int tid = threadIdx.x;
    const int r0 = blockIdx.x * 32;
#pragma unroll
    for (int i = 0; i < 8; ++i) {
        int id = i * 256 + tid;
        int r = id >> 6, c = id & 63;
        *(float4*)&Al[r][c * 4] = *(const float4*)(A + (size_t)(r0 + r) * 256 + c * 4);
    }
    __syncthreads();
    const int col = tid % P, seg = tid / P;
    float acc[RT];
#pragma unroll
    for (int i = 0; i < RT; ++i) acc[i] = 0.f;
    for (int kb = 0; kb < 64; ++kb) {
        float w[4];
#pragma unroll
        for (int dk = 0; dk < 4; ++dk) w[dk] = W[(kb * 4 + dk) * P + col];
#pragma unroll
        for (int r = 0; r < RT; ++r) {
            float4 a = *(const float4*)&Al[seg * RT + r][kb * 4];
            acc[r] += a.x * w[0] + a.y * w[1] + a.z * w[2] + a.w * w[3];
        }
    }
#pragma unroll
    for (int r = 0; r < RT; ++r) out[(size_t)(r0 + seg * RT + r) * P + col] = acc[r];
}

// ---------- CSR gather conv (wave per dst) ----------
__global__ __launch_bounds__(256) void k_conv256(const float* __restrict__ xw, const int* __restrict__ rs,
                                                 const int* __restrict__ csrc, const float* __restrict__ dinv,
                                                 const float* __restrict__ bias, float* __restrict__ out, int relu) {
    const int lane = threadIdx.x & 63, wave = threadIdx.x >> 6;
    const int d = blockIdx.x * 4 + wave;
    const float dd = dinv[d];
    float4 acc = *(const float4*)(xw + (size_t)d * 256 + lane * 4);
    const float ws0 = dd * dd;
    acc.x *= ws0; acc.y *= ws0; acc.z *= ws0; acc.w *= ws0;
    const int beg = rs[d], end = rs[d + 1];
    for (int e = beg; e < end; ++e) {
        const int s = csrc[e];
        const float w = dinv[s] * dd;
        const float4 rv = *(const float4*)(xw + (size_t)s * 256 + lane * 4);
        acc.x += rv.x * w; acc.y += rv.y * w; acc.z += rv.z * w; acc.w += rv.w * w;
    }
    const float4 bb = *(const float4*)(bias + lane * 4);
    float4 o_;
    o_.x = acc.x + bb.x; o_.y = acc.y + bb.y; o_.z = acc.z + bb.z; o_.w = acc.w + bb.w;
    if (relu) { o_.x = fmaxf(o_.x, 0.f); o_.y = fmaxf(o_.y, 0.f); o_.z = fmaxf(o_.z, 0.f); o_.w = fmaxf(o_.w, 0.f); }
    *(float4*)(out + (size_t)d * 256 + lane * 4) = o_;
}

__global__ __launch_bounds__(256) void k_conv128(const float* __restrict__ xw, const int* __restrict__ rs,
                                                 const int* __restrict__ csrc, const float* __restrict__ dinv,
                                                 const float* __restrict__ bias, float* __restrict__ out, int relu) {
    const int lane = threadIdx.x & 63, wave = threadIdx.x >> 6;
    const int d = blockIdx.x * 4 + wave;
    const float dd = dinv[d];
    float2 acc = *(const float2*)(xw + (size_t)d * 128 + lane * 2);
    const float ws0 = dd * dd;
    acc.x *= ws0; acc.y *= ws0;
    const int beg = rs[d], end = rs[d + 1];
    for (int e = beg; e < end; ++e) {
        const int s = csrc[e];
        const float w = dinv[s] * dd;
        const float2 rv = *(const float2*)(xw + (size_t)s * 128 + lane * 2);
        acc.x += rv.x * w; acc.y += rv.y * w;
    }
    const float2 bb = *(const float2*)(bias + lane * 2);
    float2 o_;
    o_.x = acc.x + bb.x; o_.y = acc.y + bb.y;
    if (relu) { o_.x = fmaxf(o_.x, 0.f); o_.y = fmaxf(o_.y, 0.f); }
    *(float2*)(out + (size_t)d * 128 + lane * 2) = o_;
}

__global__ __launch_bounds__(256) void k_out(const float* __restrict__ h2, const float* __restrict__ ow,
                                             const float* __restrict__ ob, float* __restrict__ out) {
    const int lane = threadIdx.x & 63, wave = threadIdx.x >> 6;
    const int n = blockIdx.x * 4 + wave;
    float a = h2[(size_t)n * 128 + lane] * ow[lane] + h2[(size_t)n * 128 + 64 + lane] * ow[64 + lane];
#pragma unroll
    for (int o = 32; o; o >>= 1) a += __shfl_xor(a, o);
    if (lane == 0) out[n] = a + ob[0];
}

extern "C" void kernel_launch(void* const* d_in, const int* in_sizes, int n_in,
                              void* d_out, int out_size, void* d_ws, size_t ws_size,
                              hipStream_t stream) {
    const float* x = (const float*)d_in[0];
    const float* sadj = (const float*)d_in[1];
    const float* fadj = (const float*)d_in[2];
    const int* ei = (const int*)d_in[3];
    const float* Wih = (const float*)d_in[4];
    const float* Whh = (const float*)d_in[5];
    const float* bih = (const float*)d_in[6];
    const float* bhh = (const float*)d_in[7];
    const float* sg1W = (const float*)d_in[8];
    const float* sg1b = (const float*)d_in[9];
    const float* sg2W = (const float*)d_in[10];
    const float* sg2b = (const float*)d_in[11];
    const float* dg1W = (const float*)d_in[12];
    const float* dg1b = (const float*)d_in[13];
    const float* dg2W = (const float*)d_in[14];
    const float* dg2b = (const float*)d_in[15];
    const float* attW1 = (const float*)d_in[16];
    const float* attb1 = (const float*)d_in[17];
    const float* attW2 = (const float*)d_in[18];
    const float* gateW = (const float*)d_in[19];
    const float* gateb = (const float*)d_in[20];
    const float* g1W = (const float*)d_in[21];
    const float* g1b = (const float*)d_in[22];
    const float* g2W = (const float*)d_in[23];
    const float* g2b = (const float*)d_in[24];
    const float* outW = (const float*)d_in[25];
    const float* outb = (const float*)d_in[26];
    float* out = (float*)d_out;

    char* ws = (char*)d_ws;
    size_t off = 0;
    auto alloc = [&](size_t bytes) -> char* {
        char* p = ws + off;
        off += (bytes + 255) & ~(size_t)255;
        return p;
    };
    unsigned short* whhbf = (unsigned short*)alloc(1024 * 256 * 2);
    float* xc = (float*)alloc(NN * 4);
    float* s1 = (float*)alloc(NN * 4);
    float* f1 = (float*)alloc(NN * 4);
    int* degi = (int*)alloc(NN * 4);
    int* rows = (int*)alloc((NN + 256) * 4);
    int* curs = (int*)alloc(NN * 4);
    float* dinv = (float*)alloc(NN * 4);
    int* csrc = (int*)alloc((size_t)EE * 4);
    float* hl = (float*)alloc((size_t)NN * 256 * 4);
    unsigned short* BsT = (unsigned short*)alloc((size_t)256 * NN * 2);
    unsigned short* BdT = (unsigned short*)alloc((size_t)256 * NN * 2);
    float* gs = (float*)alloc((size_t)NN * 256 * 4);
    float* gd = (float*)alloc((size_t)NN * 256 * 4);
    float* fused = (float*)alloc((size_t)NN * 256 * 4);
    float* xw1 = hl;          // reuse (h_lstm dead after k_fuse)
    float* h1 = gs;           // reuse (gs dead after k_fuse)
    float* xw2 = (float*)BsT; // reuse (BsT dead after k_adjgemm)
    float* h2 = (float*)BdT;  // reuse

    k_prep_whh<<<256, 256, 0, stream>>>(Whh, whhbf);
    k_prep_misc<<<32, 256, 0, stream>>>(x, xc, degi);
    k_hist<<<1024, 256, 0, stream>>>(ei, degi);
    k_scan<<<1, 1024, 0, stream>>>(degi, rows, curs, dinv);
    k_fill<<<1024, 256, 0, stream>>>(ei, curs, csrc);
    k_lstm<<<128, 256, 0, stream>>>(x, whhbf, Wih, bih, bhh, hl);
    k_matvec<<<dim3(8192, 2), 256, 0, stream>>>(sadj, fadj, xc, s1, f1);
    k_buildB<<<dim3(1024, 2), 256, 0, stream>>>(s1, f1, sg1W, sg1b, sg2W, dg1W, dg1b, dg2W, BsT, BdT);
    k_adjgemm<<<256, 256, 0, stream>>>(sadj, fadj, BsT, BdT, sg2b, dg2b, gs, gd);
    k_fuse<<<2048, 256, 0, stream>>>(gs, gd, hl, attW1, attb1, attW2, gateW, gateb, fused);
    k_xw<256><<<256, 256, 0, stream>>>(fused, g1W, xw1);
    k_conv256<<<2048, 256, 0, stream>>>(xw1, rows, csrc, dinv, g1b, h1, 1);
    k_xw<128><<<256, 256, 0, stream>>>(h1, g2W, xw2);
    k_conv128<<<2048, 256, 0, stream>>>(xw2, rows, csrc, dinv, g2b, h2, 0);
    k_out<<<2048, 256, 0, stream>>>(h2, outW, outb, out);
}

// Round 2
// 1896.624 us; speedup vs baseline: 2.0407x; 2.0407x over previous
//
#include <hip/hip_runtime.h>
#include <cstdint>

#define NN 8192
#define TT 64
#define EE 262144

typedef __attribute__((ext_vector_type(8))) short short8;
typedef __attribute__((ext_vector_type(4))) float f32x4;

__device__ __forceinline__ f32x4 mfma16(short8 a, short8 b, f32x4 c) {
    return __builtin_amdgcn_mfma_f32_16x16x32_bf16(a, b, c, 0, 0, 0);
}
__device__ __forceinline__ unsigned short f2bf(float f) {
    uint32_t u = __float_as_uint(f);
    u += 0x7fff + ((u >> 16) & 1);
    return (unsigned short)(u >> 16);
}
__device__ __forceinline__ float bf2f(unsigned short s) {
    return __uint_as_float(((uint32_t)s) << 16);
}
__device__ __forceinline__ float sigm(float x) { return 1.0f / (1.0f + __expf(-x)); }
__device__ __forceinline__ float tanh_(float x) { float e = __expf(2.0f * x); return 1.0f - 2.0f / (e + 1.0f); }

// ---------- prep: swizzle W_hh into per-(wave,gate,ks) lane-ordered bf16 chunks ----------
// dest group d = ((wv*4+g)*8+ks)*64 + lane ; each group = 8 bf16 = 16 B, holds
// whh[g*256 + wv*16 + cc][ks*32 + q*8 .. +8] for lane=(q<<4)|cc.
__global__ void k_prep_whh(const float* __restrict__ w, unsigned short* __restrict__ o) {
    int d = blockIdx.x * 256 + threadIdx.x;  // 128 blocks -> 32768 groups
    int lane = d & 63, ks = (d >> 6) & 7, g = (d >> 9) & 3, wv = d >> 11;
    int cc = lane & 15, q = lane >> 4;
    const float* src = w + (size_t)(g * 256 + wv * 16 + cc) * 256 + ks * 32 + q * 8;
    uint32_t p[4];
#pragma unroll
    for (int i = 0; i < 4; ++i)
        p[i] = (uint32_t)f2bf(src[2 * i]) | ((uint32_t)f2bf(src[2 * i + 1]) << 16);
    *(uint4*)(o + (size_t)d * 8) = make_uint4(p[0], p[1], p[2], p[3]);
}

__global__ void k_prep_misc(const float* __restrict__ x, float* __restrict__ xc, int* __restrict__ deg) {
    int i = blockIdx.x * 256 + threadIdx.x;
    if (i < NN) { xc[i] = x[i * TT + (TT - 1)]; deg[i] = 0; }
}

__global__ void k_hist(const int* __restrict__ ei, int* __restrict__ deg) {
    int e = blockIdx.x * 256 + threadIdx.x;
    if (e < EE) atomicAdd(&deg[ei[EE + e]], 1);
}

__global__ __launch_bounds__(1024) void k_scan(const int* __restrict__ deg, int* __restrict__ row_start,
                                               int* __restrict__ cursor, float* __restrict__ dinv) {
    __shared__ int sc[1024];
    int tid = threadIdx.x;
    int base[8]; int s = 0;
#pragma unroll
    for (int i = 0; i < 8; ++i) { base[i] = s; s += deg[tid * 8 + i]; }
    sc[tid] = s; __syncthreads();
    for (int off = 1; off < 1024; off <<= 1) {
        int v = (tid >= off) ? sc[tid - off] : 0;
        __syncthreads();
        sc[tid] += v;
        __syncthreads();
    }
    int excl = (tid > 0) ? sc[tid - 1] : 0;
#pragma unroll
    for (int i = 0; i < 8; ++i) {
        int rsv = excl + base[i];
        row_start[tid * 8 + i] = rsv;
        cursor[tid * 8 + i] = rsv;
        dinv[tid * 8 + i] = rsqrtf((float)(deg[tid * 8 + i] + 1));
    }
    if (tid == 0) row_start[NN] = sc[1023];
}

__global__ void k_fill(const int* __restrict__ ei, int* __restrict__ cursor, int* __restrict__ csr_src) {
    int e = blockIdx.x * 256 + threadIdx.x;
    if (e < EE) {
        int d = ei[EE + e];
        int pos = atomicAdd(&cursor[d], 1);
        csr_src[pos] = ei[e];
    }
}

// ---------- LSTM v2: 256 blocks x 32 rows, 1024 threads (16 waves, 4/SIMD) ----------
// Wave wv owns h-units wv*16+cc (cc=lane&15) for all 4 gates; weights streamed
// from L2 as coalesced 1 KB chunks (pre-swizzled). h tile + x tile in LDS.
__global__ __launch_bounds__(1024) void k_lstm(
    const float* __restrict__ x, const unsigned short* __restrict__ whhs,
    const float* __restrict__ wih, const float* __restrict__ bih,
    const float* __restrict__ bhh, float* __restrict__ hout) {
    __shared__ unsigned short hl[32][264];  // stride 132 dwords == 4 mod 32: even bank tiling
    __shared__ float xl[32][64];
    const int tid = threadIdx.x;
    const int m0 = blockIdx.x * 32;
    const int wv = tid >> 6, lane = tid & 63;
    const int q = lane >> 4, cc = lane & 15;

    // stage x tile (32 rows x 64 t)
#pragma unroll
    for (int i = tid; i < 32 * 64; i += 1024) {
        int r = i >> 6, c = i & 63;
        xl[r][c] = x[(size_t)(m0 + r) * TT + c];
    }
    for (int i = tid; i < 32 * 264; i += 1024) ((unsigned short*)hl)[i] = 0;

    // per-thread gate params for unit = wv*16+cc
    const int unit = wv * 16 + cc;
    float wihr[4], biasr[4];
#pragma unroll
    for (int g = 0; g < 4; ++g) {
        wihr[g] = wih[g * 256 + unit];
        biasr[g] = bih[g * 256 + unit] + bhh[g * 256 + unit];
    }
    __syncthreads();

    float c_reg[8];
#pragma unroll
    for (int i = 0; i < 8; ++i) c_reg[i] = 0.f;

    const unsigned short* wp = whhs + (size_t)wv * (4 * 8 * 64 * 8);

    for (int t = 0; t < TT; ++t) {
        f32x4 acc[8];  // [rt*4+g]
#pragma unroll
        for (int i = 0; i < 8; ++i) acc[i] = (f32x4)(0.0f);
#pragma unroll
        for (int ks = 0; ks < 8; ++ks) {
            short8 a0 = *(const short8*)&hl[cc][ks * 32 + q * 8];
            short8 a1 = *(const short8*)&hl[16 + cc][ks * 32 + q * 8];
#pragma unroll
            for (int g = 0; g < 4; ++g) {
                const short8 bfr = *(const short8*)(wp + ((size_t)(g * 8 + ks) * 64 + lane) * 8);
                acc[g] = mfma16(a0, bfr, acc[g]);
                acc[4 + g] = mfma16(a1, bfr, acc[4 + g]);
            }
        }
        unsigned short hs[8];
#pragma unroll
        for (int rt = 0; rt < 2; ++rt) {
#pragma unroll
            for (int r = 0; r < 4; ++r) {
                const int row = rt * 16 + q * 4 + r;
                const float xv = xl[row][t];
                float vi = acc[rt * 4 + 0][r] + xv * wihr[0] + biasr[0];
                float vf = acc[rt * 4 + 1][r] + xv * wihr[1] + biasr[1];
                float vg = acc[rt * 4 + 2][r] + xv * wihr[2] + biasr[2];
                float vo = acc[rt * 4 + 3][r] + xv * wihr[3] + biasr[3];
                float cv = sigm(vf) * c_reg[rt * 4 + r] + sigm(vi) * tanh_(vg);
                c_reg[rt * 4 + r] = cv;
                hs[rt * 4 + r] = f2bf(sigm(vo) * tanh_(cv));
            }
        }
        __syncthreads();  // all MFMA reads of h(t) done
#pragma unroll
        for (int rt = 0; rt < 2; ++rt)
#pragma unroll
            for (int r = 0; r < 4; ++r)
                hl[rt * 16 + q * 4 + r][unit] = hs[rt * 4 + r];
        __syncthreads();  // h(t+1) visible
    }
#pragma unroll
    for (int i = tid; i < 32 * 256; i += 1024) {
        int r = i >> 8, k = i & 255;
        hout[(size_t)(m0 + r) * 256 + k] = bf2f(hl[r][k]);
    }
}

// ---------- s1 = sadj@xc, f1 = fadj@xc ----------
__global__ __launch_bounds__(256) void k_matvec(const float* __restrict__ sadj, const float* __restrict__ fadj,
                                                const float* __restrict__ xc, float* __restrict__ s1,
                                                float* __restrict__ f1) {
    const float* A = blockIdx.y ? fadj : sadj;
    float* out = blockIdx.y ? f1 : s1;
    const int row = blockIdx.x, tid = threadIdx.x;
    const float4* a4 = (const float4*)(A + (size_t)row * NN);
    const float4* x4 = (const float4*)xc;
    float acc = 0.f;
#pragma unroll
    for (int c = 0; c < 8; ++c) {
        float4 a = a4[c * 256 + tid];
        float4 v = x4[c * 256 + tid];
        acc += a.x * v.x + a.y * v.y + a.z * v.z + a.w * v.w;
    }
#pragma unroll
    for (int o = 32; o; o >>= 1) acc += __shfl_xor(acc, o);
    __shared__ float red[4];
    if ((tid & 63) == 0) red[tid >> 6] = acc;
    __syncthreads();
    if (tid == 0) out[row] = red[0] + red[1] + red[2] + red[3];
}

// ---------- BsT[j][n] = (relu(s1[n]*W1 + b1) @ W2)[n][j] in bf16, transposed ----------
__global__ __launch_bounds__(256) void k_buildB(
    const float* __restrict__ s1, const float* __restrict__ f1,
    const float* __restrict__ sg1W, const float* __restrict__ sg1b, const float* __restrict__ sg2W,
    const float* __restrict__ dg1W, const float* __restrict__ dg1b, const float* __restrict__ dg2W,
    unsigned short* __restrict__ BsT, unsigned short* __restrict__ BdT) {
    const int mat = blockIdx.y;
    const float* sv = mat ? f1 : s1;
    const float* W1 = mat ? dg1W : sg1W;
    const float* b1 = mat ? dg1b : sg1b;
    const float* W2 = mat ? dg2W : sg2W;
    unsigned short* BT = mat ? BdT : BsT;
    const int n0 = blockIdx.x * 8;
    const int tid = threadIdx.x;
    __shared__ float h[8][256];
    __shared__ float sl[8];
    if (tid < 8) sl[tid] = sv[n0 + tid];
    __syncthreads();
    {
        float w1 = W1[tid], bb = b1[tid];
#pragma unroll
        for (int g = 0; g < 8; ++g) h[g][tid] = fmaxf(sl[g] * w1 + bb, 0.f);
    }
    __syncthreads();
    float acc[8];
#pragma unroll
    for (int g = 0; g < 8; ++g) acc[g] = 0.f;
    for (int kb = 0; kb < 64; ++kb) {
        float4 h4[8];
#pragma unroll
        for (int g = 0; g < 8; ++g) h4[g] = *(const float4*)&h[g][kb * 4];
#pragma unroll
        for (int dk = 0; dk < 4; ++dk) {
            float w = W2[(kb * 4 + dk) * 256 + tid];
#pragma unroll
            for (int g = 0; g < 8; ++g) acc[g] += ((const float*)&h4[g])[dk] * w;
        }
    }
    uint32_t p[4];
#pragma unroll
    for (int i = 0; i < 4; ++i)
        p[i] = (uint32_t)f2bf(acc[2 * i]) | ((uint32_t)f2bf(acc[2 * i + 1]) << 16);
    uint4 pv = make_uint4(p[0], p[1], p[2], p[3]);
    *(uint4*)(BT + (size_t)tid * NN + n0) = pv;
}

// ---------- gs = sadj @ Bs + b2 (fp32 A converted to bf16 on the fly) ----------
__global__ __launch_bounds__(256, 1) void k_adjgemm(
    const float* __restrict__ sadj, const float* __restrict__ fadj,
    const unsigned short* __restrict__ BsT, const unsigned short* __restrict__ BdT,
    const float* __restrict__ sb2, const float* __restrict__ db2,
    float* __restrict__ gs, float* __restrict__ gd) {
    const int bx = blockIdx.x;
    const int mat = bx >> 7, strip = bx & 127;
    const float* A = mat ? fadj : sadj;
    const unsigned short* BT = mat ? BdT : BsT;
    const float* bias = mat ? db2 : sb2;
    float* C = mat ? gd : gs;
    __shared__ unsigned short Al[2][64][40];
    __shared__ unsigned short Bl[2][256][40];
    const int tid = threadIdx.x;
    const int lane = tid & 63, wave = tid >> 6;
    const int q = lane >> 4, cc = lane & 15;

    f32x4 acc[16];
#pragma unroll
    for (int i = 0; i < 16; ++i) acc[i] = (f32x4)(0.0f);

    float4 apf[2]; uint4 bpf[4];
#pragma unroll
    for (int c = 0; c < 2; ++c) {
        int id = c * 256 + tid; int r = id >> 3, kc = id & 7;
        apf[c] = *(const float4*)(A + (size_t)(strip * 64 + r) * NN + kc * 4);
    }
#pragma unroll
    for (int i = 0; i < 4; ++i) {
        int id = i * 256 + tid; int col = id >> 2, j = id & 3;
        bpf[i] = *(const uint4*)(BT + (size_t)col * NN + j * 8);
    }
    int buf = 0;
#pragma unroll
    for (int c = 0; c < 2; ++c) {
        int id = c * 256 + tid; int r = id >> 3, kc = id & 7;
        uint32_t p0 = (uint32_t)f2bf(apf[c].x) | ((uint32_t)f2bf(apf[c].y) << 16);
        uint32_t p1 = (uint32_t)f2bf(apf[c].z) | ((uint32_t)f2bf(apf[c].w) << 16);
        *(uint2*)&Al[0][r][kc * 4] = make_uint2(p0, p1);
    }
#pragma unroll
    for (int i = 0; i < 4; ++i) {
        int id = i * 256 + tid; int col = id >> 2, j = id & 3;
        *(uint4*)&Bl[0][col][j * 8] = bpf[i];
    }
    __syncthreads();

    for (int kb = 0; kb < 256; ++kb) {
        const int k1 = (kb + 1) * 32;
        if (kb < 255) {
#pragma unroll
            for (int c = 0; c < 2; ++c) {
                int id = c * 256 + tid; int r = id >> 3, kc = id & 7;
                apf[c] = *(const float4*)(A + (size_t)(strip * 64 + r) * NN + k1 + kc * 4);
            }
#pragma unroll
            for (int i = 0; i < 4; ++i) {
                int id = i * 256 + tid; int col = id >> 2, j = id & 3;
                bpf[i] = *(const uint4*)(BT + (size_t)col * NN + k1 + j * 8);
            }
        }
        short8 af[4], bfm[4];
#pragma unroll
        for (int rt = 0; rt < 4; ++rt) af[rt] = *(const short8*)&Al[buf][rt * 16 + cc][q * 8];
#pragma unroll
        for (int ct = 0; ct < 4; ++ct) bfm[ct] = *(const short8*)&Bl[buf][wave * 64 + ct * 16 + cc][q * 8];
#pragma unroll
        for (int rt = 0; rt < 4; ++rt)
#pragma unroll
            for (int ct = 0; ct < 4; ++ct)
                acc[rt * 4 + ct] = mfma16(af[rt], bfm[ct], acc[rt * 4 + ct]);
        if (kb < 255) {
#pragma unroll
            for (int c = 0; c < 2; ++c) {
                int id = c * 256 + tid; int r = id >> 3, kc = id & 7;
                uint32_t p0 = (uint32_t)f2bf(apf[c].x) | ((uint32_t)f2bf(apf[c].y) << 16);
                uint32_t p1 = (uint32_t)f2bf(apf[c].z) | ((uint32_t)f2bf(apf[c].w) << 16);
                *(uint2*)&Al[buf ^ 1][r][kc * 4] = make_uint2(p0, p1);
            }
#pragma unroll
            for (int i = 0; i < 4; ++i) {
                int id = i * 256 + tid; int col = id >> 2, j = id & 3;
                *(uint4*)&Bl[buf ^ 1][col][j * 8] = bpf[i];
            }
            __syncthreads();
            buf ^= 1;
        }
    }
#pragma unroll
    for (int rt = 0; rt < 4; ++rt)
#pragma unroll
        for (int ct = 0; ct < 4; ++ct) {
            const int gcol = wave * 64 + ct * 16 + cc;
            const float bb = bias[gcol];
#pragma unroll
            for (int r = 0; r < 4; ++r) {
                const int grow = strip * 64 + rt * 16 + q * 4 + r;
                C[(size_t)grow * 256 + gcol] = acc[rt * 4 + ct][r] + bb;
            }
        }
}

// ---------- attention + gate + fuse (wave per node) ----------
__global__ __launch_bounds__(256) void k_fuse(
    const float* __restrict__ gs, const float* __restrict__ gd, const float* __restrict__ hlstm,
    const float* __restrict__ attW1, const float* __restrict__ attb1, const float* __restrict__ attW2,
    const float* __restrict__ gateW, const float* __restrict__ gateb, float* __restrict__ fused) {
    const int tid = threadIdx.x, lane = tid & 63, wave = tid >> 6;
    const int n = blockIdx.x * 4 + wave;
    float4 vs = *(const float4*)(gs + (size_t)n * 256 + lane * 4);
    float4 vd = *(const float4*)(gd + (size_t)n * 256 + lane * 4);
    float vsa[4] = {vs.x, vs.y, vs.z, vs.w};
    float vda[4] = {vd.x, vd.y, vd.z, vd.w};
    float vca[4];
#pragma unroll
    for (int i = 0; i < 4; ++i) vca[i] = 0.5f * (vsa[i] + vda[i]);
    float y[3][16];
#pragma unroll
    for (int v = 0; v < 3; ++v)
#pragma unroll
        for (int hh = 0; hh < 16; ++hh) y[v][hh] = 0.f;
#pragma unroll
    for (int t = 0; t < 4; ++t) {
        const int k = lane * 4 + t;
#pragma unroll
        for (int hb = 0; hb < 4; ++hb) {
            float4 w = *(const float4*)(attW1 + k * 16 + hb * 4);
            float wa[4] = {w.x, w.y, w.z, w.w};
#pragma unroll
            for (int j = 0; j < 4; ++j) {
                y[0][hb * 4 + j] += vsa[t] * wa[j];
                y[1][hb * 4 + j] += vda[t] * wa[j];
                y[2][hb * 4 + j] += vca[t] * wa[j];
            }
        }
    }
#pragma unroll
    for (int v = 0; v < 3; ++v)
#pragma unroll
        for (int hh = 0; hh < 16; ++hh) {
            float a = y[v][hh];
#pragma unroll
            for (int o = 32; o; o >>= 1) a += __shfl_xor(a, o);
            y[v][hh] = a;
        }
    float wv[3];
#pragma unroll
    for (int v = 0; v < 3; ++v) {
        float s = 0.f;
#pragma unroll
        for (int hh = 0; hh < 16; ++hh) s += tanh_(y[v][hh] + attb1[hh]) * attW2[hh];
        wv[v] = s;
    }
    float mx = fmaxf(wv[0], fmaxf(wv[1], wv[2]));
    float e0 = __expf(wv[0] - mx), e1 = __expf(wv[1] - mx), e2 = __expf(wv[2] - mx);
    float inv = 1.f / (e0 + e1 + e2);
    float b0 = e0 * inv, b1v = e1 * inv, b2 = e2 * inv;
    float gf[4];
#pragma unroll
    for (int i = 0; i < 4; ++i) gf[i] = b0 * vsa[i] + b1v * vda[i] + b2 * vca[i];
    float4 hv4 = *(const float4*)(hlstm + (size_t)n * 256 + lane * 4);
    float hva[4] = {hv4.x, hv4.y, hv4.z, hv4.w};
    float4 w0 = *(const float4*)(gateW + lane * 4);
    float4 w1 = *(const float4*)(gateW + 256 + lane * 4);
    float part = gf[0] * w0.x + gf[1] * w0.y + gf[2] * w0.z + gf[3] * w0.w +
                 hva[0] * w1.x + hva[1] * w1.y + hva[2] * w1.z + hva[3] * w1.w;
#pragma unroll
    for (int o = 32; o; o >>= 1) part += __shfl_xor(part, o);
    float z = sigm(part + gateb[0]);
    float4 fo;
    fo.x = z * gf[0] + (1.f - z) * hva[0];
    fo.y = z * gf[1] + (1.f - z) * hva[1];
    fo.z = z * gf[2] + (1.f - z) * hva[2];
    fo.w = z * gf[3] + (1.f - z) * hva[3];
    *(float4*)(fused + (size_t)n * 256 + lane * 4) = fo;
}

// ---------- small GEMM xw = A(8192xK=256) @ W(256xP) ----------
template <int P>
__global__ __launch_bounds__(256) void k_xw(const float* __restrict__ A, const float* __restrict__ W,
                                            float* __restrict__ out) {
    constexpr int CPT = 256 / P;
    constexpr int RT = 32 / CPT;
    __shared__ float Al[32][256];
    const int tid = threadIdx.x;
    const int r0 = blockIdx.x * 32;
#pragma unroll
    for (int i = 0; i < 8; ++i) {
        int id = i * 256 + tid;
        int r = id >> 6, c = id & 63;
        *(float4*)&Al[r][c * 4] = *(const float4*)(A + (size_t)(r0 + r) * 256 + c * 4);
    }
    __syncthreads();
    const int col = tid % P, seg = tid / P;
    float acc[RT];
#pragma unroll
    for (int i = 0; i < RT; ++i) acc[i] = 0.f;
    for (int kb = 0; kb < 64; ++kb) {
        float w[4];
#pragma unroll
        for (int dk = 0; dk < 4; ++dk) w[dk] = W[(kb * 4 + dk) * P + col];
#pragma unroll
        for (int r = 0; r < RT; ++r) {
            float4 a = *(const float4*)&Al[seg * RT + r][kb * 4];
            acc[r] += a.x * w[0] + a.y * w[1] + a.z * w[2] + a.w * w[3];
        }
    }
#pragma unroll
    for (int r = 0; r < RT; ++r) out[(size_t)(r0 + seg * RT + r) * P + col] = acc[r];
}

// ---------- CSR gather conv (wave per dst) ----------
__global__ __launch_bounds__(256) void k_conv256(const float* __restrict__ xw, const int* __restrict__ rs,
                                                 const int* __restrict__ csrc, const float* __restrict__ dinv,
                                                 const float* __restrict__ bias, float* __restrict__ out, int relu) {
    const int lane = threadIdx.x & 63, wave = threadIdx.x >> 6;
    const int d = blockIdx.x * 4 + wave;
    const float dd = dinv[d];
    float4 acc = *(const float4*)(xw + (size_t)d * 256 + lane * 4);
    const float ws0 = dd * dd;
    acc.x *= ws0; acc.y *= ws0; acc.z *= ws0; acc.w *= ws0;
    const int beg = rs[d], end = rs[d + 1];
    for (int e = beg; e < end; ++e) {
        const int s = csrc[e];
        const float w = dinv[s] * dd;
        const float4 rv = *(const float4*)(xw + (size_t)s * 256 + lane * 4);
        acc.x += rv.x * w; acc.y += rv.y * w; acc.z += rv.z * w; acc.w += rv.w * w;
    }
    const float4 bb = *(const float4*)(bias + lane * 4);
    float4 o_;
    o_.x = acc.x + bb.x; o_.y = acc.y + bb.y; o_.z = acc.z + bb.z; o_.w = acc.w + bb.w;
    if (relu) { o_.x = fmaxf(o_.x, 0.f); o_.y = fmaxf(o_.y, 0.f); o_.z = fmaxf(o_.z, 0.f); o_.w = fmaxf(o_.w, 0.f); }
    *(float4*)(out + (size_t)d * 256 + lane * 4) = o_;
}

__global__ __launch_bounds__(256) void k_conv128(const float* __restrict__ xw, const int* __restrict__ rs,
                                                 const int* __restrict__ csrc, const float* __restrict__ dinv,
                                                 const float* __restrict__ bias, float* __restrict__ out, int relu) {
    const int lane = threadIdx.x & 63, wave = threadIdx.x >> 6;
    const int d = blockIdx.x * 4 + wave;
    const float dd = dinv[d];
    float2 acc = *(const float2*)(xw + (size_t)d * 128 + lane * 2);
    const float ws0 = dd * dd;
    acc.x *= ws0; acc.y *= ws0;
    const int beg = rs[d], end = rs[d + 1];
    for (int e = beg; e < end; ++e) {
        const int s = csrc[e];
        const float w = dinv[s] * dd;
        const float2 rv = *(const float2*)(xw + (size_t)s * 128 + lane * 2);
        acc.x += rv.x * w; acc.y += rv.y * w;
    }
    const float2 bb = *(const float2*)(bias + lane * 2);
    float2 o_;
    o_.x = acc.x + bb.x; o_.y = acc.y + bb.y;
    if (relu) { o_.x = fmaxf(o_.x, 0.f); o_.y = fmaxf(o_.y, 0.f); }
    *(float2*)(out + (size_t)d * 128 + lane * 2) = o_;
}

__global__ __launch_bounds__(256) void k_out(const float* __restrict__ h2, const float* __restrict__ ow,
                                             const float* __restrict__ ob, float* __restrict__ out) {
    const int lane = threadIdx.x & 63, wave = threadIdx.x >> 6;
    const int n = blockIdx.x * 4 + wave;
    float a = h2[(size_t)n * 128 + lane] * ow[lane] + h2[(size_t)n * 128 + 64 + lane] * ow[64 + lane];
#pragma unroll
    for (int o = 32; o; o >>= 1) a += __shfl_xor(a, o);
    if (lane == 0) out[n] = a + ob[0];
}

extern "C" void kernel_launch(void* const* d_in, const int* in_sizes, int n_in,
                              void* d_out, int out_size, void* d_ws, size_t ws_size,
                              hipStream_t stream) {
    const float* x = (const float*)d_in[0];
    const float* sadj = (const float*)d_in[1];
    const float* fadj = (const float*)d_in[2];
    const int* ei = (const int*)d_in[3];
    const float* Wih = (const float*)d_in[4];
    const float* Whh = (const float*)d_in[5];
    const float* bih = (const float*)d_in[6];
    const float* bhh = (const float*)d_in[7];
    const float* sg1W = (const float*)d_in[8];
    const float* sg1b = (const float*)d_in[9];
    const float* sg2W = (const float*)d_in[10];
    const float* sg2b = (const float*)d_in[11];
    const float* dg1W = (const float*)d_in[12];
    const float* dg1b = (const float*)d_in[13];
    const float* dg2W = (const float*)d_in[14];
    const float* dg2b = (const float*)d_in[15];
    const float* attW1 = (const float*)d_in[16];
    const float* attb1 = (const float*)d_in[17];
    const float* attW2 = (const float*)d_in[18];
    const float* gateW = (const float*)d_in[19];
    const float* gateb = (const float*)d_in[20];
    const float* g1W = (const float*)d_in[21];
    const float* g1b = (const float*)d_in[22];
    const float* g2W = (const float*)d_in[23];
    const float* g2b = (const float*)d_in[24];
    const float* outW = (const float*)d_in[25];
    const float* outb = (const float*)d_in[26];
    float* out = (float*)d_out;

    char* ws = (char*)d_ws;
    size_t off = 0;
    auto alloc = [&](size_t bytes) -> char* {
        char* p = ws + off;
        off += (bytes + 255) & ~(size_t)255;
        return p;
    };
    unsigned short* whhs = (unsigned short*)alloc(1024 * 256 * 2);
    float* xc = (float*)alloc(NN * 4);
    float* s1 = (float*)alloc(NN * 4);
    float* f1 = (float*)alloc(NN * 4);
    int* degi = (int*)alloc(NN * 4);
    int* rows = (int*)alloc((NN + 256) * 4);
    int* curs = (int*)alloc(NN * 4);
    float* dinv = (float*)alloc(NN * 4);
    int* csrc = (int*)alloc((size_t)EE * 4);
    float* hl = (float*)alloc((size_t)NN * 256 * 4);
    unsigned short* BsT = (unsigned short*)alloc((size_t)256 * NN * 2);
    unsigned short* BdT = (unsigned short*)alloc((size_t)256 * NN * 2);
    float* gs = (float*)alloc((size_t)NN * 256 * 4);
    float* gd = (float*)alloc((size_t)NN * 256 * 4);
    float* fused = (float*)alloc((size_t)NN * 256 * 4);
    float* xw1 = hl;          // reuse (h_lstm dead after k_fuse)
    float* h1 = gs;           // reuse (gs dead after k_fuse)
    float* xw2 = (float*)BsT; // reuse (BsT dead after k_adjgemm)
    float* h2 = (float*)BdT;  // reuse

    k_prep_whh<<<128, 256, 0, stream>>>(Whh, whhs);
    k_prep_misc<<<32, 256, 0, stream>>>(x, xc, degi);
    k_hist<<<1024, 256, 0, stream>>>(ei, degi);
    k_scan<<<1, 1024, 0, stream>>>(degi, rows, curs, dinv);
    k_fill<<<1024, 256, 0, stream>>>(ei, curs, csrc);
    k_lstm<<<256, 1024, 0, stream>>>(x, whhs, Wih, bih, bhh, hl);
    k_matvec<<<dim3(8192, 2), 256, 0, stream>>>(sadj, fadj, xc, s1, f1);
    k_buildB<<<dim3(1024, 2), 256, 0, stream>>>(s1, f1, sg1W, sg1b, sg2W, dg1W, dg1b, dg2W, BsT, BdT);
    k_adjgemm<<<256, 256, 0, stream>>>(sadj, fadj, BsT, BdT, sg2b, dg2b, gs, gd);
    k_fuse<<<2048, 256, 0, stream>>>(gs, gd, hl, attW1, attb1, attW2, gateW, gateb, fused);
    k_xw<256><<<256, 256, 0, stream>>>(fused, g1W, xw1);
    k_conv256<<<2048, 256, 0, stream>>>(xw1, rows, csrc, dinv, g1b, h1, 1);
    k_xw<128><<<256, 256, 0, stream>>>(h1, g2W, xw2);
    k_conv128<<<2048, 256, 0, stream>>>(xw2, rows, csrc, dinv, g2b, h2, 0);
    k_out<<<2048, 256, 0, stream>>>(h2, outW, outb, out);
}